// Round 3
// baseline (1107.383 us; speedup 1.0000x reference)
//
#include <hip/hip_runtime.h>

typedef short bf16x8 __attribute__((ext_vector_type(8)));
typedef float floatx4 __attribute__((ext_vector_type(4)));
typedef unsigned short u16x4 __attribute__((ext_vector_type(4)));
typedef unsigned short u16x8 __attribute__((ext_vector_type(8)));

__device__ __forceinline__ unsigned short f2bf(float f) {
  union { float f; unsigned int u; } v;
  v.f = f;
  unsigned int u = v.u + (0x7FFFu + ((v.u >> 16) & 1u));  // RNE
  return (unsigned short)(u >> 16);
}
__device__ __forceinline__ float bf2f(unsigned short h) {
  union { unsigned int u; float f; } v; v.u = ((unsigned int)h) << 16; return v.f;
}
__device__ __forceinline__ bf16x8 pack8(float4 a, float4 b) {
  u16x8 h;
  h[0] = f2bf(a.x); h[1] = f2bf(a.y); h[2] = f2bf(a.z); h[3] = f2bf(a.w);
  h[4] = f2bf(b.x); h[5] = f2bf(b.y); h[6] = f2bf(b.z); h[7] = f2bf(b.w);
  union { u16x8 u; bf16x8 s; } cv; cv.u = h; return cv.s;
}

// ---------------------------------------------------------------------------
// Weights -> bf16 fragment layout Wf[g][n][j] = W[g*8+j][n]  (g=k/8, j=k%8)
// ---------------------------------------------------------------------------
__global__ __launch_bounds__(256) void prep_weights(
    const float* __restrict__ mW1, const float* __restrict__ mW2,
    const float* __restrict__ nW1, const float* __restrict__ nW2,
    unsigned short* __restrict__ W1f, unsigned short* __restrict__ W2f,
    unsigned short* __restrict__ NW1f, unsigned short* __restrict__ NW2f) {
  int idx = blockIdx.x * 256 + threadIdx.x;
  if (idx < 24576) {
    int j = idx & 7, n = (idx >> 3) & 127, g = idx >> 10;
    W1f[idx] = f2bf(mW1[(g * 8 + j) * 128 + n]);
  } else if (idx < 32768) {
    int t = idx - 24576;
    int j = t & 7, n = (t >> 3) & 63, g = t >> 9;
    W2f[t] = f2bf(mW2[(g * 8 + j) * 64 + n]);
  } else if (idx < 49152) {
    int t = idx - 32768;
    int j = t & 7, n = (t >> 3) & 127, g = t >> 10;
    NW1f[t] = f2bf(nW1[(g * 8 + j) * 128 + n]);
  } else if (idx < 57344) {
    int t = idx - 49152;
    int j = t & 7, n = (t >> 3) & 63, g = t >> 9;
    NW2f[t] = f2bf(nW2[(g * 8 + j) * 64 + n]);
  }
}

__global__ __launch_bounds__(256) void conv_nodes(
    const float* __restrict__ nodes, unsigned short* __restrict__ nodes_bf, int total4) {
  int i = (blockIdx.x * 256 + threadIdx.x) * 4;
  if (i < total4) {
    float4 v = *(const float4*)(nodes + i);
    u16x4 h; h[0] = f2bf(v.x); h[1] = f2bf(v.y); h[2] = f2bf(v.z); h[3] = f2bf(v.w);
    *(u16x4*)(nodes_bf + i) = h;
  }
}

// --------------------------- CSR build (sort by receiver) -------------------
__global__ __launch_bounds__(256) void k_count(
    const int* __restrict__ rcv, int* __restrict__ cnt, int E) {
  int e = blockIdx.x * 256 + threadIdx.x;
  if (e < E) atomicAdd(&cnt[rcv[e]], 1);
}

// per-256-block exclusive scan; block totals to aux
__global__ __launch_bounds__(256) void k_scan1(
    const int* __restrict__ cnt, int* __restrict__ rowptr, int* __restrict__ aux, int N) {
  __shared__ int wsum[4];
  int tid = threadIdx.x, lane = tid & 63, wid = tid >> 6;
  int i = blockIdx.x * 256 + tid;
  int v = (i < N) ? cnt[i] : 0;
  int x = v;
#pragma unroll
  for (int d = 1; d < 64; d <<= 1) {
    int t = __shfl_up(x, d);
    if (lane >= d) x += t;
  }
  if (lane == 63) wsum[wid] = x;
  __syncthreads();
  int off = 0;
#pragma unroll
  for (int k = 0; k < 4; ++k) if (k < wid) off += wsum[k];
  if (i < N) rowptr[i] = off + x - v;
  if (tid == 0) aux[blockIdx.x] = wsum[0] + wsum[1] + wsum[2] + wsum[3];
}

// single-block exclusive scan of NB block-totals (NB <= 512)
__global__ __launch_bounds__(512) void k_scan2(int* __restrict__ aux, int NB) {
  __shared__ int s[512];
  int t = threadIdx.x;
  int orig = (t < NB) ? aux[t] : 0;
  s[t] = orig;
  __syncthreads();
  for (int d = 1; d < 512; d <<= 1) {
    int v = (t >= d) ? s[t - d] : 0;
    __syncthreads();
    s[t] += v;
    __syncthreads();
  }
  if (t < NB) aux[t] = s[t] - orig;  // exclusive
}

__global__ __launch_bounds__(256) void k_scan3(
    int* __restrict__ rowptr, const int* __restrict__ aux, int N, int E) {
  int i = blockIdx.x * 256 + threadIdx.x;
  if (i < N) rowptr[i] += aux[i >> 8];
  if (i == 0) rowptr[N] = E;
}

__global__ __launch_bounds__(256) void k_scatter(
    const int* __restrict__ snd, const int* __restrict__ rcv,
    const int* __restrict__ rowptr, int* __restrict__ cur,
    int* __restrict__ s_snd, int* __restrict__ s_rcv, int* __restrict__ s_eid, int E) {
  int e = blockIdx.x * 256 + threadIdx.x;
  if (e < E) {
    int r = rcv[e];
    int pos = rowptr[r] + atomicAdd(&cur[r], 1);
    s_snd[pos] = snd[e];
    s_rcv[pos] = r;
    s_eid[pos] = e;
  }
}

// ---------------------------------------------------------------------------
// Edge kernel (receiver-sorted): no atomics. Gathers sender/receiver features
// (receiver gather is clustered by the sort), gathers edge features by
// original id, runs the message MLP with MFMA, writes bf16 messages
// COALESCED at the sorted position.
// ---------------------------------------------------------------------------
__global__ __launch_bounds__(256, 3) void edge_kernel(
    const float* __restrict__ edges, const unsigned short* __restrict__ nodes_bf,
    const int* __restrict__ s_snd, const int* __restrict__ s_rcv,
    const int* __restrict__ s_eid,
    const unsigned short* __restrict__ W1f, const unsigned short* __restrict__ W2f,
    const float* __restrict__ b1, const float* __restrict__ b2,
    unsigned short* __restrict__ msg, int E) {
  __shared__ __align__(16) unsigned short Hl[128 * 136];  // 34.8 KB; reused for msg staging

  const int tid = threadIdx.x;
  const int p0 = blockIdx.x * 128;
  const int w = tid >> 6, lane = tid & 63;
  const int col = lane & 15, quad = lane >> 4;
  const int wm = w & 1, wn = w >> 1;

  int sndi[4], rcvi[4], eidi[4];
#pragma unroll
  for (int mt = 0; mt < 4; ++mt) {
    int p = p0 + wm * 64 + mt * 16 + col;
    p = p < E ? p : E - 1;
    sndi[mt] = s_snd[p]; rcvi[mt] = s_rcv[p]; eidi[mt] = s_eid[p];
  }

  floatx4 z4 = {0.f, 0.f, 0.f, 0.f};
  floatx4 acc1[4][4];
#pragma unroll
  for (int mt = 0; mt < 4; ++mt)
#pragma unroll
    for (int nt = 0; nt < 4; ++nt) acc1[mt][nt] = z4;

  // GEMM1, K=192: ks 0,1 = sender feats; 2,3 = receiver feats; 4,5 = edge feats
#pragma unroll
  for (int ks = 0; ks < 4; ++ks) {
    bf16x8 a[4], b[4];
#pragma unroll
    for (int mt = 0; mt < 4; ++mt) {
      int nd = (ks < 2) ? sndi[mt] : rcvi[mt];
      a[mt] = *(const bf16x8*)&nodes_bf[(size_t)nd * 64 + (ks & 1) * 32 + quad * 8];
    }
#pragma unroll
    for (int nt = 0; nt < 4; ++nt)
      b[nt] = *(const bf16x8*)&W1f[ks * 4096 + quad * 1024 + (wn * 64 + nt * 16 + col) * 8];
#pragma unroll
    for (int mt = 0; mt < 4; ++mt)
#pragma unroll
      for (int nt = 0; nt < 4; ++nt)
        acc1[mt][nt] = __builtin_amdgcn_mfma_f32_16x16x32_bf16(a[mt], b[nt], acc1[mt][nt], 0, 0, 0);
  }
#pragma unroll
  for (int ks = 4; ks < 6; ++ks) {
    bf16x8 a[4], b[4];
#pragma unroll
    for (int mt = 0; mt < 4; ++mt) {
      const float* p = edges + (size_t)eidi[mt] * 64 + (ks - 4) * 32 + quad * 8;
      float4 v0 = *(const float4*)p;
      float4 v1 = *(const float4*)(p + 4);
      a[mt] = pack8(v0, v1);
    }
#pragma unroll
    for (int nt = 0; nt < 4; ++nt)
      b[nt] = *(const bf16x8*)&W1f[ks * 4096 + quad * 1024 + (wn * 64 + nt * 16 + col) * 8];
#pragma unroll
    for (int mt = 0; mt < 4; ++mt)
#pragma unroll
      for (int nt = 0; nt < 4; ++nt)
        acc1[mt][nt] = __builtin_amdgcn_mfma_f32_16x16x32_bf16(a[mt], b[nt], acc1[mt][nt], 0, 0, 0);
  }

  // bias + ReLU -> Hl (bf16), C-layout -> A-layout via LDS
#pragma unroll
  for (int nt = 0; nt < 4; ++nt) {
    float bias = b1[wn * 64 + nt * 16 + col];
#pragma unroll
    for (int mt = 0; mt < 4; ++mt)
#pragma unroll
      for (int r = 0; r < 4; ++r) {
        float v = acc1[mt][nt][r] + bias;
        v = v > 0.f ? v : 0.f;
        Hl[(wm * 64 + mt * 16 + quad * 4 + r) * 136 + wn * 64 + nt * 16 + col] = f2bf(v);
      }
  }
  __syncthreads();

  floatx4 acc2[4][2];
#pragma unroll
  for (int mt = 0; mt < 4; ++mt) { acc2[mt][0] = z4; acc2[mt][1] = z4; }

  // GEMM2, K=128
#pragma unroll
  for (int ks = 0; ks < 4; ++ks) {
    bf16x8 a[4], b[2];
#pragma unroll
    for (int mt = 0; mt < 4; ++mt)
      a[mt] = *(const bf16x8*)&Hl[(wm * 64 + mt * 16 + col) * 136 + ks * 32 + quad * 8];
#pragma unroll
    for (int nt = 0; nt < 2; ++nt)
      b[nt] = *(const bf16x8*)&W2f[ks * 2048 + quad * 512 + (wn * 32 + nt * 16 + col) * 8];
#pragma unroll
    for (int mt = 0; mt < 4; ++mt)
#pragma unroll
      for (int nt = 0; nt < 2; ++nt)
        acc2[mt][nt] = __builtin_amdgcn_mfma_f32_16x16x32_bf16(a[mt], b[nt], acc2[mt][nt], 0, 0, 0);
  }
  __syncthreads();  // Hl reads done; reuse as message staging (stride 72)

  float bs0 = b2[wn * 32 + col];
  float bs1 = b2[wn * 32 + 16 + col];
#pragma unroll
  for (int mt = 0; mt < 4; ++mt)
#pragma unroll
    for (int r = 0; r < 4; ++r) {
      int row = wm * 64 + mt * 16 + quad * 4 + r;
      float v0 = acc2[mt][0][r] + bs0; v0 = v0 > 0.f ? v0 : 0.f;
      float v1 = acc2[mt][1][r] + bs1; v1 = v1 > 0.f ? v1 : 0.f;
      Hl[row * 72 + wn * 32 + col] = f2bf(v0);
      Hl[row * 72 + wn * 32 + 16 + col] = f2bf(v1);
    }
  __syncthreads();

  // coalesced 16B store-out of messages
  {
    int row = tid >> 1, c0 = (tid & 1) * 32;
    if (p0 + row < E) {
#pragma unroll
      for (int k = 0; k < 4; ++k)
        *(u16x8*)&msg[(size_t)(p0 + row) * 64 + c0 + k * 8] =
            *(const u16x8*)&Hl[row * 72 + c0 + k * 8];
    }
  }
}

// ---------------------------------------------------------------------------
// Node kernel: phase 1 streams each node's contiguous message segment
// (receiver-sorted -> sequential reads), fp32 accumulate -> agg_s (bf16, LDS).
// Phase 2: node MLP (MFMA) + LayerNorm + residual.
// ---------------------------------------------------------------------------
__global__ __launch_bounds__(256, 3) void node_kernel(
    const float* __restrict__ nodes, const unsigned short* __restrict__ nodes_bf,
    const unsigned short* __restrict__ msg, const int* __restrict__ rowptr,
    const unsigned short* __restrict__ W1f, const unsigned short* __restrict__ W2f,
    const float* __restrict__ b1, const float* __restrict__ b2,
    const float* __restrict__ ln_s, const float* __restrict__ ln_o,
    float* __restrict__ out, int N) {
  __shared__ __align__(16) unsigned short Hl[128 * 136];  // agg_s (stride 72) then hidden
  __shared__ float Ls1[128][2];
  __shared__ float Ls2[128][2];

  const int tid = threadIdx.x;
  const int n0 = blockIdx.x * 128;
  const int w = tid >> 6, lane = tid & 63;
  const int col = lane & 15, quad = lane >> 4;
  const int wm = w & 1, wn = w >> 1;

  // ---- phase 1: segment sums (wave w -> 32 nodes, lane = feature) ----
  for (int k = 0; k < 32; ++k) {
    int nl = w * 32 + k;
    int n = n0 + nl;
    float acc = 0.f;
    if (n < N) {
      int s = rowptr[n], e = rowptr[n + 1];
      int i = s;
      for (; i + 4 <= e; i += 4) {
        float a0 = bf2f(msg[(size_t)(i + 0) * 64 + lane]);
        float a1 = bf2f(msg[(size_t)(i + 1) * 64 + lane]);
        float a2 = bf2f(msg[(size_t)(i + 2) * 64 + lane]);
        float a3 = bf2f(msg[(size_t)(i + 3) * 64 + lane]);
        acc += (a0 + a1) + (a2 + a3);
      }
      for (; i < e; ++i) acc += bf2f(msg[(size_t)i * 64 + lane]);
    }
    Hl[nl * 72 + lane] = f2bf(acc);
  }
  __syncthreads();

  int arow[4];
#pragma unroll
  for (int mt = 0; mt < 4; ++mt) {
    int r = n0 + wm * 64 + mt * 16 + col;
    arow[mt] = r < N ? r : N - 1;
  }

  floatx4 z4 = {0.f, 0.f, 0.f, 0.f};
  floatx4 acc1[4][4];
#pragma unroll
  for (int mt = 0; mt < 4; ++mt)
#pragma unroll
    for (int nt = 0; nt < 4; ++nt) acc1[mt][nt] = z4;

  // GEMM1, K=128: ks 0,1 = node feats (global bf16); 2,3 = agg (LDS bf16)
#pragma unroll
  for (int ks = 0; ks < 2; ++ks) {
    bf16x8 a[4], b[4];
#pragma unroll
    for (int mt = 0; mt < 4; ++mt)
      a[mt] = *(const bf16x8*)&nodes_bf[(size_t)arow[mt] * 64 + ks * 32 + quad * 8];
#pragma unroll
    for (int nt = 0; nt < 4; ++nt)
      b[nt] = *(const bf16x8*)&W1f[ks * 4096 + quad * 1024 + (wn * 64 + nt * 16 + col) * 8];
#pragma unroll
    for (int mt = 0; mt < 4; ++mt)
#pragma unroll
      for (int nt = 0; nt < 4; ++nt)
        acc1[mt][nt] = __builtin_amdgcn_mfma_f32_16x16x32_bf16(a[mt], b[nt], acc1[mt][nt], 0, 0, 0);
  }
#pragma unroll
  for (int ks = 2; ks < 4; ++ks) {
    bf16x8 a[4], b[4];
#pragma unroll
    for (int mt = 0; mt < 4; ++mt)
      a[mt] = *(const bf16x8*)&Hl[(wm * 64 + mt * 16 + col) * 72 + (ks - 2) * 32 + quad * 8];
#pragma unroll
    for (int nt = 0; nt < 4; ++nt)
      b[nt] = *(const bf16x8*)&W1f[ks * 4096 + quad * 1024 + (wn * 64 + nt * 16 + col) * 8];
#pragma unroll
    for (int mt = 0; mt < 4; ++mt)
#pragma unroll
      for (int nt = 0; nt < 4; ++nt)
        acc1[mt][nt] = __builtin_amdgcn_mfma_f32_16x16x32_bf16(a[mt], b[nt], acc1[mt][nt], 0, 0, 0);
  }
  __syncthreads();  // agg_s reads done before Hl is overwritten

#pragma unroll
  for (int nt = 0; nt < 4; ++nt) {
    float bias = b1[wn * 64 + nt * 16 + col];
#pragma unroll
    for (int mt = 0; mt < 4; ++mt)
#pragma unroll
      for (int r = 0; r < 4; ++r) {
        float v = acc1[mt][nt][r] + bias;
        v = v > 0.f ? v : 0.f;
        Hl[(wm * 64 + mt * 16 + quad * 4 + r) * 136 + wn * 64 + nt * 16 + col] = f2bf(v);
      }
  }
  __syncthreads();

  floatx4 acc2[4][2];
#pragma unroll
  for (int mt = 0; mt < 4; ++mt) { acc2[mt][0] = z4; acc2[mt][1] = z4; }

#pragma unroll
  for (int ks = 0; ks < 4; ++ks) {
    bf16x8 a[4], b[2];
#pragma unroll
    for (int mt = 0; mt < 4; ++mt)
      a[mt] = *(const bf16x8*)&Hl[(wm * 64 + mt * 16 + col) * 136 + ks * 32 + quad * 8];
#pragma unroll
    for (int nt = 0; nt < 2; ++nt)
      b[nt] = *(const bf16x8*)&W2f[ks * 2048 + quad * 512 + (wn * 32 + nt * 16 + col) * 8];
#pragma unroll
    for (int mt = 0; mt < 4; ++mt)
#pragma unroll
      for (int nt = 0; nt < 2; ++nt)
        acc2[mt][nt] = __builtin_amdgcn_mfma_f32_16x16x32_bf16(a[mt], b[nt], acc2[mt][nt], 0, 0, 0);
  }

  float y[4][2][4];
  float bs0 = b2[wn * 32 + col];
  float bs1 = b2[wn * 32 + 16 + col];
#pragma unroll
  for (int mt = 0; mt < 4; ++mt)
#pragma unroll
    for (int r = 0; r < 4; ++r) {
      y[mt][0][r] = acc2[mt][0][r] + bs0;
      y[mt][1][r] = acc2[mt][1][r] + bs1;
    }

#pragma unroll
  for (int mt = 0; mt < 4; ++mt)
#pragma unroll
    for (int r = 0; r < 4; ++r) {
      float p1 = y[mt][0][r] + y[mt][1][r];
      float p2 = y[mt][0][r] * y[mt][0][r] + y[mt][1][r] * y[mt][1][r];
#pragma unroll
      for (int m = 1; m <= 8; m <<= 1) {
        p1 += __shfl_xor(p1, m);
        p2 += __shfl_xor(p2, m);
      }
      if (col == 0) {
        int row = wm * 64 + mt * 16 + quad * 4 + r;
        Ls1[row][wn] = p1;
        Ls2[row][wn] = p2;
      }
    }
  __syncthreads();

  float lsv0 = ln_s[wn * 32 + col], lsv1 = ln_s[wn * 32 + 16 + col];
  float lov0 = ln_o[wn * 32 + col], lov1 = ln_o[wn * 32 + 16 + col];
#pragma unroll
  for (int mt = 0; mt < 4; ++mt)
#pragma unroll
    for (int r = 0; r < 4; ++r) {
      int row = wm * 64 + mt * 16 + quad * 4 + r;
      int gi = n0 + row;
      float s1 = Ls1[row][0] + Ls1[row][1];
      float s2 = Ls2[row][0] + Ls2[row][1];
      float mean = s1 * (1.f / 64.f);
      float var = s2 * (1.f / 64.f) - mean * mean;
      float rstd = rsqrtf(var + 1e-5f);
      if (gi < N) {
        int j0 = wn * 32 + col;
        float o0 = (y[mt][0][r] - mean) * rstd * lsv0 + lov0 + nodes[(size_t)gi * 64 + j0];
        float o1 = (y[mt][1][r] - mean) * rstd * lsv1 + lov1 + nodes[(size_t)gi * 64 + j0 + 16];
        out[(size_t)gi * 64 + j0] = o0;
        out[(size_t)gi * 64 + j0 + 16] = o1;
      }
    }
}

extern "C" void kernel_launch(void* const* d_in, const int* in_sizes, int n_in,
                              void* d_out, int out_size, void* d_ws, size_t ws_size,
                              hipStream_t stream) {
  const float* nodes     = (const float*)d_in[0];
  const float* edges     = (const float*)d_in[1];
  const int*   senders   = (const int*)d_in[2];
  const int*   receivers = (const int*)d_in[3];
  const float* msg_W1    = (const float*)d_in[4];
  const float* msg_b1    = (const float*)d_in[5];
  const float* msg_W2    = (const float*)d_in[6];
  const float* msg_b2    = (const float*)d_in[7];
  const float* node_W1   = (const float*)d_in[8];
  const float* node_b1   = (const float*)d_in[9];
  const float* node_W2   = (const float*)d_in[10];
  const float* node_b2   = (const float*)d_in[11];
  const float* ln_scale  = (const float*)d_in[12];
  const float* ln_offset = (const float*)d_in[13];

  const int N = in_sizes[0] / 64;
  const int E = in_sizes[2];
  const int NB = (N + 255) / 256;

  // ---- workspace carve-up (256B-aligned) ----
  char* p = (char*)d_ws;
  auto take = [&](size_t bytes) {
    char* q = p;
    p += (bytes + 255) & ~(size_t)255;
    return q;
  };
  unsigned short* W1f      = (unsigned short*)take(24576 * 2);
  unsigned short* W2f      = (unsigned short*)take(8192 * 2);
  unsigned short* NW1f     = (unsigned short*)take(16384 * 2);
  unsigned short* NW2f     = (unsigned short*)take(8192 * 2);
  unsigned short* nodes_bf = (unsigned short*)take((size_t)N * 64 * 2);
  int* cnt      = (int*)take((size_t)NB * 256 * 4);
  int* cur      = (int*)take((size_t)NB * 256 * 4);
  int* rowptr   = (int*)take(((size_t)N + 1) * 4);
  int* aux      = (int*)take((size_t)NB * 4);
  int* s_snd    = (int*)take((size_t)E * 4);
  int* s_rcv    = (int*)take((size_t)E * 4);
  int* s_eid    = (int*)take((size_t)E * 4);
  unsigned short* msg = (unsigned short*)take((size_t)E * 64 * 2);

  hipMemsetAsync(cnt, 0, (size_t)NB * 256 * 4, stream);
  hipMemsetAsync(cur, 0, (size_t)NB * 256 * 4, stream);

  prep_weights<<<224, 256, 0, stream>>>(msg_W1, msg_W2, node_W1, node_W2, W1f, W2f, NW1f, NW2f);
  conv_nodes<<<(N * 64 + 1023) / 1024, 256, 0, stream>>>(nodes, nodes_bf, N * 64);

  k_count<<<(E + 255) / 256, 256, 0, stream>>>(receivers, cnt, E);
  k_scan1<<<NB, 256, 0, stream>>>(cnt, rowptr, aux, N);
  k_scan2<<<1, 512, 0, stream>>>(aux, NB);
  k_scan3<<<NB, 256, 0, stream>>>(rowptr, aux, N, E);
  k_scatter<<<(E + 255) / 256, 256, 0, stream>>>(senders, receivers, rowptr, cur,
                                                 s_snd, s_rcv, s_eid, E);

  edge_kernel<<<(E + 127) / 128, 256, 0, stream>>>(edges, nodes_bf, s_snd, s_rcv, s_eid,
                                                   W1f, W2f, msg_b1, msg_b2, msg, E);
  node_kernel<<<(N + 127) / 128, 256, 0, stream>>>(nodes, nodes_bf, msg, rowptr,
                                                   NW1f, NW2f, node_b1, node_b2,
                                                   ln_scale, ln_offset, (float*)d_out, N);
}